// Round 1
// baseline (761.400 us; speedup 1.0000x reference)
//
#include <hip/hip_runtime.h>

// GCN forward: h = relu(spmm(x@w1)+b1); out = spmm(h@w2)+b2
// CSR built on-device per launch (ws is re-poisoned every call).

// ---------------- CSR build ----------------
__global__ void k_zero(int* __restrict__ p, int n) {
  int i = blockIdx.x * blockDim.x + threadIdx.x;
  if (i < n) p[i] = 0;
}

__global__ void k_count(const int* __restrict__ row, int* __restrict__ deg, int ne) {
  int e = blockIdx.x * blockDim.x + threadIdx.x;
  if (e < ne) atomicAdd(&deg[row[e]], 1);
}

// per-block exclusive scan of 1024 elems (256 thr x 4), emits block sums
__global__ __launch_bounds__(256)
void k_scan_block(const int* __restrict__ deg, int* __restrict__ out,
                  int* __restrict__ bsums, int n) {
  __shared__ int sd[256];
  int t = threadIdx.x;
  int base = blockIdx.x * 1024 + t * 4;
  int v0 = (base + 0 < n) ? deg[base + 0] : 0;
  int v1 = (base + 1 < n) ? deg[base + 1] : 0;
  int v2 = (base + 2 < n) ? deg[base + 2] : 0;
  int v3 = (base + 3 < n) ? deg[base + 3] : 0;
  int s = v0 + v1 + v2 + v3;
  sd[t] = s;
  __syncthreads();
  for (int off = 1; off < 256; off <<= 1) {
    int x = (t >= off) ? sd[t - off] : 0;
    __syncthreads();
    sd[t] += x;
    __syncthreads();
  }
  int excl = sd[t] - s;
  if (base + 0 < n) out[base + 0] = excl;
  if (base + 1 < n) out[base + 1] = excl + v0;
  if (base + 2 < n) out[base + 2] = excl + v0 + v1;
  if (base + 3 < n) out[base + 3] = excl + v0 + v1 + v2;
  if (t == 255) bsums[blockIdx.x] = sd[255];
}

// single-block exclusive scan of the (<=256) block sums
__global__ __launch_bounds__(256)
void k_scan_sums(int* __restrict__ bsums, int nb) {
  __shared__ int sd[256];
  int t = threadIdx.x;
  int v = (t < nb) ? bsums[t] : 0;
  sd[t] = v;
  __syncthreads();
  for (int off = 1; off < 256; off <<= 1) {
    int x = (t >= off) ? sd[t - off] : 0;
    __syncthreads();
    sd[t] += x;
    __syncthreads();
  }
  if (t < nb) bsums[t] = sd[t] - v;
}

__global__ void k_scan_add(int* __restrict__ rp, int* __restrict__ cursor,
                           const int* __restrict__ bsums, int n) {
  int i = blockIdx.x * blockDim.x + threadIdx.x;
  if (i < n) {
    int v = rp[i] + bsums[i >> 10];
    rp[i] = v;
    cursor[i] = v;
  }
}

__global__ void k_scatter(const int* __restrict__ row, const int* __restrict__ col,
                          const float* __restrict__ vals, int* __restrict__ cursor,
                          int* __restrict__ col_s, float* __restrict__ val_s, int ne) {
  int e = blockIdx.x * blockDim.x + threadIdx.x;
  if (e < ne) {
    int r = row[e];
    int p = atomicAdd(&cursor[r], 1);
    col_s[p] = col[e];
    val_s[p] = vals[e];
  }
}

// ---------------- GEMM1: C[M,128] = A[M,256] @ B[256,128] ----------------
__global__ __launch_bounds__(256)
void gemm1_kernel(const float* __restrict__ A, const float* __restrict__ B,
                  float* __restrict__ C, int M) {
  __shared__ float As[16][132];   // transposed A tile, padded (write conflicts)
  __shared__ float Bs[16][128];
  const int tid = threadIdx.x;
  const int tx = tid & 15;
  const int ty = tid >> 4;
  const int m0 = blockIdx.x * 128;
  float acc[8][8];
#pragma unroll
  for (int i = 0; i < 8; ++i)
#pragma unroll
    for (int j = 0; j < 8; ++j) acc[i][j] = 0.f;

  for (int kt = 0; kt < 256; kt += 16) {
#pragma unroll
    for (int l = 0; l < 2; ++l) {
      int id = tid + l * 256;          // 0..511
      int r  = id >> 2;                // 0..127
      int c4 = (id & 3) << 2;          // 0,4,8,12
      int gm = m0 + r;
      float4 a = make_float4(0.f, 0.f, 0.f, 0.f);
      if (gm < M) a = *(const float4*)(A + (size_t)gm * 256 + kt + c4);
      As[c4 + 0][r] = a.x; As[c4 + 1][r] = a.y;
      As[c4 + 2][r] = a.z; As[c4 + 3][r] = a.w;
    }
#pragma unroll
    for (int l = 0; l < 2; ++l) {
      int id = tid + l * 256;
      int r  = id >> 5;                // 0..15
      int n4 = (id & 31) << 2;         // 0..124
      *(float4*)(&Bs[r][n4]) = *(const float4*)(B + (size_t)(kt + r) * 128 + n4);
    }
    __syncthreads();
#pragma unroll
    for (int kk = 0; kk < 16; ++kk) {
      float a[8], b[8];
      float4 t0 = *(const float4*)(&As[kk][ty * 8]);
      float4 t1 = *(const float4*)(&As[kk][ty * 8 + 4]);
      a[0]=t0.x; a[1]=t0.y; a[2]=t0.z; a[3]=t0.w;
      a[4]=t1.x; a[5]=t1.y; a[6]=t1.z; a[7]=t1.w;
      float4 u0 = *(const float4*)(&Bs[kk][tx * 8]);
      float4 u1 = *(const float4*)(&Bs[kk][tx * 8 + 4]);
      b[0]=u0.x; b[1]=u0.y; b[2]=u0.z; b[3]=u0.w;
      b[4]=u1.x; b[5]=u1.y; b[6]=u1.z; b[7]=u1.w;
#pragma unroll
      for (int i = 0; i < 8; ++i)
#pragma unroll
        for (int j = 0; j < 8; ++j)
          acc[i][j] = fmaf(a[i], b[j], acc[i][j]);
    }
    __syncthreads();
  }
#pragma unroll
  for (int i = 0; i < 8; ++i) {
    int gm = m0 + ty * 8 + i;
    if (gm < M) {
      float4 s0 = make_float4(acc[i][0], acc[i][1], acc[i][2], acc[i][3]);
      float4 s1 = make_float4(acc[i][4], acc[i][5], acc[i][6], acc[i][7]);
      *(float4*)(C + (size_t)gm * 128 + tx * 8)     = s0;
      *(float4*)(C + (size_t)gm * 128 + tx * 8 + 4) = s1;
    }
  }
}

// ---------------- GEMM2: C[M,64] = A[M,128] @ B[128,64] ----------------
__global__ __launch_bounds__(256)
void gemm2_kernel(const float* __restrict__ A, const float* __restrict__ B,
                  float* __restrict__ C, int M) {
  __shared__ float As[16][132];
  __shared__ float Bs[16][64];
  const int tid = threadIdx.x;
  const int tx = tid & 15;
  const int ty = tid >> 4;
  const int m0 = blockIdx.x * 128;
  float acc[8][4];
#pragma unroll
  for (int i = 0; i < 8; ++i)
#pragma unroll
    for (int j = 0; j < 4; ++j) acc[i][j] = 0.f;

  for (int kt = 0; kt < 128; kt += 16) {
#pragma unroll
    for (int l = 0; l < 2; ++l) {
      int id = tid + l * 256;
      int r  = id >> 2;
      int c4 = (id & 3) << 2;
      int gm = m0 + r;
      float4 a = make_float4(0.f, 0.f, 0.f, 0.f);
      if (gm < M) a = *(const float4*)(A + (size_t)gm * 128 + kt + c4);
      As[c4 + 0][r] = a.x; As[c4 + 1][r] = a.y;
      As[c4 + 2][r] = a.z; As[c4 + 3][r] = a.w;
    }
    {
      int r  = tid >> 4;               // 0..15
      int n4 = (tid & 15) << 2;        // 0..60
      *(float4*)(&Bs[r][n4]) = *(const float4*)(B + (size_t)(kt + r) * 64 + n4);
    }
    __syncthreads();
#pragma unroll
    for (int kk = 0; kk < 16; ++kk) {
      float a[8], b[4];
      float4 t0 = *(const float4*)(&As[kk][ty * 8]);
      float4 t1 = *(const float4*)(&As[kk][ty * 8 + 4]);
      a[0]=t0.x; a[1]=t0.y; a[2]=t0.z; a[3]=t0.w;
      a[4]=t1.x; a[5]=t1.y; a[6]=t1.z; a[7]=t1.w;
      float4 u0 = *(const float4*)(&Bs[kk][tx * 4]);
      b[0]=u0.x; b[1]=u0.y; b[2]=u0.z; b[3]=u0.w;
#pragma unroll
      for (int i = 0; i < 8; ++i)
#pragma unroll
        for (int j = 0; j < 4; ++j)
          acc[i][j] = fmaf(a[i], b[j], acc[i][j]);
    }
    __syncthreads();
  }
#pragma unroll
  for (int i = 0; i < 8; ++i) {
    int gm = m0 + ty * 8 + i;
    if (gm < M) {
      float4 s0 = make_float4(acc[i][0], acc[i][1], acc[i][2], acc[i][3]);
      *(float4*)(C + (size_t)gm * 64 + tx * 4) = s0;
    }
  }
}

// ---------------- SPMM1 + relu(+b1): one wave per row, 128 feats ----------------
__global__ __launch_bounds__(256)
void k_spmm1(const int* __restrict__ rp, const int* __restrict__ deg,
             const int* __restrict__ col_s, const float* __restrict__ val_s,
             const float* __restrict__ h, const float* __restrict__ b1,
             float* __restrict__ agg, int n) {
  int r = blockIdx.x * 4 + (threadIdx.x >> 6);
  if (r >= n) return;
  int lane = threadIdx.x & 63;
  int s = rp[r], d = deg[r];
  float a0 = 0.f, a1 = 0.f;
  for (int t = 0; t < d; ++t) {
    int e = s + t;
    float v = val_s[e];
    size_t c = (size_t)col_s[e] * 128;
    a0 = fmaf(v, h[c + lane], a0);
    a1 = fmaf(v, h[c + lane + 64], a1);
  }
  agg[(size_t)r * 128 + lane]      = fmaxf(a0 + b1[lane], 0.f);
  agg[(size_t)r * 128 + lane + 64] = fmaxf(a1 + b1[lane + 64], 0.f);
}

// ---------------- SPMM2 + b2: one wave per row, 64 feats ----------------
__global__ __launch_bounds__(256)
void k_spmm2(const int* __restrict__ rp, const int* __restrict__ deg,
             const int* __restrict__ col_s, const float* __restrict__ val_s,
             const float* __restrict__ h2, const float* __restrict__ b2,
             float* __restrict__ out, int n) {
  int r = blockIdx.x * 4 + (threadIdx.x >> 6);
  if (r >= n) return;
  int lane = threadIdx.x & 63;
  int s = rp[r], d = deg[r];
  float a = 0.f;
  for (int t = 0; t < d; ++t) {
    int e = s + t;
    float v = val_s[e];
    a = fmaf(v, h2[(size_t)col_s[e] * 64 + lane], a);
  }
  out[(size_t)r * 64 + lane] = a + b2[lane];
}

extern "C" void kernel_launch(void* const* d_in, const int* in_sizes, int n_in,
                              void* d_out, int out_size, void* d_ws, size_t ws_size,
                              hipStream_t stream) {
  const float* x        = (const float*)d_in[0];
  const float* w1       = (const float*)d_in[1];
  const float* b1       = (const float*)d_in[2];
  const float* w2       = (const float*)d_in[3];
  const float* b2       = (const float*)d_in[4];
  const int*   adj_row  = (const int*)d_in[5];
  const int*   adj_col  = (const int*)d_in[6];
  const float* adj_vals = (const float*)d_in[7];
  float* out = (float*)d_out;

  const int N  = in_sizes[0] / 256;   // 100000
  const int NE = in_sizes[5];         // 1600000

  // workspace carve (256B aligned). h2 aliases h (dead after spmm1).
  char* p = (char*)d_ws;
  auto carve = [&](size_t bytes) {
    char* r = p;
    p += (bytes + 255) & ~(size_t)255;
    return (void*)r;
  };
  float* h      = (float*)carve((size_t)N * 128 * 4);
  float* agg    = (float*)carve((size_t)N * 128 * 4);
  int*   col_s  = (int*)  carve((size_t)NE * 4);
  float* val_s  = (float*)carve((size_t)NE * 4);
  int*   rp     = (int*)  carve((size_t)N * 4);
  int*   deg    = (int*)  carve((size_t)N * 4);
  int*   cursor = (int*)  carve((size_t)N * 4);
  int*   bsums  = (int*)  carve(1024);
  float* h2 = h;

  const int nb_scan = (N + 1023) / 1024;   // 98 (<=256 required by k_scan_sums)

  hipLaunchKernelGGL(k_zero,       dim3((N + 255) / 256),  dim3(256), 0, stream, deg, N);
  hipLaunchKernelGGL(k_count,      dim3((NE + 255) / 256), dim3(256), 0, stream, adj_row, deg, NE);
  hipLaunchKernelGGL(k_scan_block, dim3(nb_scan),          dim3(256), 0, stream, deg, rp, bsums, N);
  hipLaunchKernelGGL(k_scan_sums,  dim3(1),                dim3(256), 0, stream, bsums, nb_scan);
  hipLaunchKernelGGL(k_scan_add,   dim3((N + 255) / 256),  dim3(256), 0, stream, rp, cursor, bsums, N);
  hipLaunchKernelGGL(k_scatter,    dim3((NE + 255) / 256), dim3(256), 0, stream,
                     adj_row, adj_col, adj_vals, cursor, col_s, val_s, NE);

  hipLaunchKernelGGL(gemm1_kernel, dim3((N + 127) / 128),  dim3(256), 0, stream, x, w1, h, N);
  hipLaunchKernelGGL(k_spmm1,      dim3((N + 3) / 4),      dim3(256), 0, stream,
                     rp, deg, col_s, val_s, h, b1, agg, N);
  hipLaunchKernelGGL(gemm2_kernel, dim3((N + 127) / 128),  dim3(256), 0, stream, agg, w2, h2, N);
  hipLaunchKernelGGL(k_spmm2,      dim3((N + 3) / 4),      dim3(256), 0, stream,
                     rp, deg, col_s, val_s, h2, b2, out, N);
}

// Round 2
// 608.162 us; speedup vs baseline: 1.2520x; 1.2520x over previous
//
#include <hip/hip_runtime.h>

// GCN forward: h = relu(spmm(x@w1)+b1); out = spmm(h@w2)+b2
// CSR built on-device per launch. Intermediates h/agg/h2 stored bf16-packed.

typedef unsigned int uint;

__device__ inline uint f2bf(float f) {
  uint u = __float_as_uint(f);
  return (u + 0x7fffu + ((u >> 16) & 1u)) >> 16;   // RNE
}
__device__ inline uint pkbf(float lo, float hi) { return f2bf(lo) | (f2bf(hi) << 16); }
__device__ inline float bf_lo(uint u) { return __uint_as_float(u << 16); }
__device__ inline float bf_hi(uint u) { return __uint_as_float(u & 0xffff0000u); }

// ---------------- CSR build ----------------
__global__ void k_zero(int* __restrict__ p, int n) {
  int i = blockIdx.x * blockDim.x + threadIdx.x;
  if (i < n) p[i] = 0;
}

__global__ void k_count(const int* __restrict__ row, int* __restrict__ deg, int ne) {
  int e = blockIdx.x * blockDim.x + threadIdx.x;
  if (e < ne) atomicAdd(&deg[row[e]], 1);
}

__global__ __launch_bounds__(256)
void k_scan_block(const int* __restrict__ deg, int* __restrict__ out,
                  int* __restrict__ bsums, int n) {
  __shared__ int sd[256];
  int t = threadIdx.x;
  int base = blockIdx.x * 1024 + t * 4;
  int v0 = (base + 0 < n) ? deg[base + 0] : 0;
  int v1 = (base + 1 < n) ? deg[base + 1] : 0;
  int v2 = (base + 2 < n) ? deg[base + 2] : 0;
  int v3 = (base + 3 < n) ? deg[base + 3] : 0;
  int s = v0 + v1 + v2 + v3;
  sd[t] = s;
  __syncthreads();
  for (int off = 1; off < 256; off <<= 1) {
    int x = (t >= off) ? sd[t - off] : 0;
    __syncthreads();
    sd[t] += x;
    __syncthreads();
  }
  int excl = sd[t] - s;
  if (base + 0 < n) out[base + 0] = excl;
  if (base + 1 < n) out[base + 1] = excl + v0;
  if (base + 2 < n) out[base + 2] = excl + v0 + v1;
  if (base + 3 < n) out[base + 3] = excl + v0 + v1 + v2;
  if (t == 255) bsums[blockIdx.x] = sd[255];
}

__global__ __launch_bounds__(256)
void k_scan_sums(int* __restrict__ bsums, int nb) {
  __shared__ int sd[256];
  int t = threadIdx.x;
  int v = (t < nb) ? bsums[t] : 0;
  sd[t] = v;
  __syncthreads();
  for (int off = 1; off < 256; off <<= 1) {
    int x = (t >= off) ? sd[t - off] : 0;
    __syncthreads();
    sd[t] += x;
    __syncthreads();
  }
  if (t < nb) bsums[t] = sd[t] - v;
}

__global__ void k_scan_add(int* __restrict__ rp, int* __restrict__ cursor,
                           const int* __restrict__ bsums, int n) {
  int i = blockIdx.x * blockDim.x + threadIdx.x;
  if (i < n) {
    int v = rp[i] + bsums[i >> 10];
    rp[i] = v;
    cursor[i] = v;
  }
}

__global__ void k_scatter(const int* __restrict__ row, const int* __restrict__ col,
                          const float* __restrict__ vals, int* __restrict__ cursor,
                          uint2* __restrict__ edges, int ne) {
  int e = blockIdx.x * blockDim.x + threadIdx.x;
  if (e < ne) {
    int r = row[e];
    int p = atomicAdd(&cursor[r], 1);
    uint2 ev;
    ev.x = (uint)col[e];
    ev.y = __float_as_uint(vals[e]);
    edges[p] = ev;
  }
}

// ---------------- GEMM1: h_bf16[M,128] = x[M,256] @ w1[256,128] ----------------
__global__ __launch_bounds__(256)
void gemm1_kernel(const float* __restrict__ A, const float* __restrict__ B,
                  uint* __restrict__ C, int M) {
  __shared__ float As[16][132];
  __shared__ float Bs[16][128];
  const int tid = threadIdx.x;
  const int tx = tid & 15;
  const int ty = tid >> 4;
  const int m0 = blockIdx.x * 128;
  float acc[8][8];
#pragma unroll
  for (int i = 0; i < 8; ++i)
#pragma unroll
    for (int j = 0; j < 8; ++j) acc[i][j] = 0.f;

  for (int kt = 0; kt < 256; kt += 16) {
#pragma unroll
    for (int l = 0; l < 2; ++l) {
      int id = tid + l * 256;
      int r  = id >> 2;
      int c4 = (id & 3) << 2;
      int gm = m0 + r;
      float4 a = make_float4(0.f, 0.f, 0.f, 0.f);
      if (gm < M) a = *(const float4*)(A + (size_t)gm * 256 + kt + c4);
      As[c4 + 0][r] = a.x; As[c4 + 1][r] = a.y;
      As[c4 + 2][r] = a.z; As[c4 + 3][r] = a.w;
    }
#pragma unroll
    for (int l = 0; l < 2; ++l) {
      int id = tid + l * 256;
      int r  = id >> 5;
      int n4 = (id & 31) << 2;
      *(float4*)(&Bs[r][n4]) = *(const float4*)(B + (size_t)(kt + r) * 128 + n4);
    }
    __syncthreads();
#pragma unroll
    for (int kk = 0; kk < 16; ++kk) {
      float a[8], b[8];
      float4 t0 = *(const float4*)(&As[kk][ty * 8]);
      float4 t1 = *(const float4*)(&As[kk][ty * 8 + 4]);
      a[0]=t0.x; a[1]=t0.y; a[2]=t0.z; a[3]=t0.w;
      a[4]=t1.x; a[5]=t1.y; a[6]=t1.z; a[7]=t1.w;
      float4 u0 = *(const float4*)(&Bs[kk][tx * 8]);
      float4 u1 = *(const float4*)(&Bs[kk][tx * 8 + 4]);
      b[0]=u0.x; b[1]=u0.y; b[2]=u0.z; b[3]=u0.w;
      b[4]=u1.x; b[5]=u1.y; b[6]=u1.z; b[7]=u1.w;
#pragma unroll
      for (int i = 0; i < 8; ++i)
#pragma unroll
        for (int j = 0; j < 8; ++j)
          acc[i][j] = fmaf(a[i], b[j], acc[i][j]);
    }
    __syncthreads();
  }
#pragma unroll
  for (int i = 0; i < 8; ++i) {
    int gm = m0 + ty * 8 + i;
    if (gm < M) {
      uint4 w;
      w.x = pkbf(acc[i][0], acc[i][1]);
      w.y = pkbf(acc[i][2], acc[i][3]);
      w.z = pkbf(acc[i][4], acc[i][5]);
      w.w = pkbf(acc[i][6], acc[i][7]);
      *(uint4*)(C + (size_t)gm * 64 + tx * 4) = w;
    }
  }
}

// ---------------- GEMM2: h2_bf16[M,64] = agg_bf16[M,128] @ w2[128,64] ----------------
__global__ __launch_bounds__(256)
void gemm2_kernel(const uint* __restrict__ A, const float* __restrict__ B,
                  uint* __restrict__ C, int M) {
  __shared__ float As[16][132];
  __shared__ float Bs[16][64];
  const int tid = threadIdx.x;
  const int tx = tid & 15;
  const int ty = tid >> 4;
  const int m0 = blockIdx.x * 128;
  float acc[8][4];
#pragma unroll
  for (int i = 0; i < 8; ++i)
#pragma unroll
    for (int j = 0; j < 4; ++j) acc[i][j] = 0.f;

  for (int kt = 0; kt < 128; kt += 16) {
    {
      int r  = tid >> 1;             // 0..127
      int q  = (tid & 1) * 4;        // uint offset within row segment
      int gm = m0 + r;
      uint4 a = make_uint4(0, 0, 0, 0);
      if (gm < M) a = *(const uint4*)(A + (size_t)gm * 64 + (kt >> 1) + q);
      int kb = q * 2;
      As[kb + 0][r] = bf_lo(a.x); As[kb + 1][r] = bf_hi(a.x);
      As[kb + 2][r] = bf_lo(a.y); As[kb + 3][r] = bf_hi(a.y);
      As[kb + 4][r] = bf_lo(a.z); As[kb + 5][r] = bf_hi(a.z);
      As[kb + 6][r] = bf_lo(a.w); As[kb + 7][r] = bf_hi(a.w);
    }
    {
      int r  = tid >> 4;
      int n4 = (tid & 15) << 2;
      *(float4*)(&Bs[r][n4]) = *(const float4*)(B + (size_t)(kt + r) * 64 + n4);
    }
    __syncthreads();
#pragma unroll
    for (int kk = 0; kk < 16; ++kk) {
      float a[8], b[4];
      float4 t0 = *(const float4*)(&As[kk][ty * 8]);
      float4 t1 = *(const float4*)(&As[kk][ty * 8 + 4]);
      a[0]=t0.x; a[1]=t0.y; a[2]=t0.z; a[3]=t0.w;
      a[4]=t1.x; a[5]=t1.y; a[6]=t1.z; a[7]=t1.w;
      float4 u0 = *(const float4*)(&Bs[kk][tx * 4]);
      b[0]=u0.x; b[1]=u0.y; b[2]=u0.z; b[3]=u0.w;
#pragma unroll
      for (int i = 0; i < 8; ++i)
#pragma unroll
        for (int j = 0; j < 4; ++j)
          acc[i][j] = fmaf(a[i], b[j], acc[i][j]);
    }
    __syncthreads();
  }
#pragma unroll
  for (int i = 0; i < 8; ++i) {
    int gm = m0 + ty * 8 + i;
    if (gm < M) {
      uint2 w;
      w.x = pkbf(acc[i][0], acc[i][1]);
      w.y = pkbf(acc[i][2], acc[i][3]);
      *(uint2*)(C + (size_t)gm * 32 + tx * 2) = w;
    }
  }
}

// ---------------- SPMM1 + relu(+b1): one wave/row, 128 feats bf16 ----------------
__global__ __launch_bounds__(256)
void k_spmm1(const int* __restrict__ rp, const int* __restrict__ deg,
             const uint2* __restrict__ edges, const uint* __restrict__ h,
             const float* __restrict__ b1, uint* __restrict__ agg, int n) {
  int r = blockIdx.x * 4 + (threadIdx.x >> 6);
  if (r >= n) return;
  int lane = threadIdx.x & 63;
  int s = rp[r], d = deg[r];
  float a0 = 0.f, a1 = 0.f;            // feats 2*lane, 2*lane+1
  int t = 0;
  for (; t + 4 <= d; t += 4) {
    uint2 e0 = edges[s + t + 0];
    uint2 e1 = edges[s + t + 1];
    uint2 e2 = edges[s + t + 2];
    uint2 e3 = edges[s + t + 3];
    uint u0 = h[(size_t)e0.x * 64 + lane];
    uint u1 = h[(size_t)e1.x * 64 + lane];
    uint u2 = h[(size_t)e2.x * 64 + lane];
    uint u3 = h[(size_t)e3.x * 64 + lane];
    float v0 = __uint_as_float(e0.y), v1 = __uint_as_float(e1.y);
    float v2 = __uint_as_float(e2.y), v3 = __uint_as_float(e3.y);
    a0 = fmaf(v0, bf_lo(u0), a0); a1 = fmaf(v0, bf_hi(u0), a1);
    a0 = fmaf(v1, bf_lo(u1), a0); a1 = fmaf(v1, bf_hi(u1), a1);
    a0 = fmaf(v2, bf_lo(u2), a0); a1 = fmaf(v2, bf_hi(u2), a1);
    a0 = fmaf(v3, bf_lo(u3), a0); a1 = fmaf(v3, bf_hi(u3), a1);
  }
  for (; t < d; ++t) {
    uint2 e0 = edges[s + t];
    uint u0 = h[(size_t)e0.x * 64 + lane];
    float v0 = __uint_as_float(e0.y);
    a0 = fmaf(v0, bf_lo(u0), a0); a1 = fmaf(v0, bf_hi(u0), a1);
  }
  float2 bb = ((const float2*)b1)[lane];
  float r0 = fmaxf(a0 + bb.x, 0.f);
  float r1 = fmaxf(a1 + bb.y, 0.f);
  agg[(size_t)r * 64 + lane] = pkbf(r0, r1);
}

// ---------------- SPMM2 + b2: one wave/row, 2 half-wave edge workers ----------------
__global__ __launch_bounds__(256)
void k_spmm2(const int* __restrict__ rp, const int* __restrict__ deg,
             const uint2* __restrict__ edges, const uint* __restrict__ h2,
             const float* __restrict__ b2, float* __restrict__ out, int n) {
  int r = blockIdx.x * 4 + (threadIdx.x >> 6);
  if (r >= n) return;
  int lane = threadIdx.x & 63;
  int half = lane >> 5;
  int fl = lane & 31;                  // feat pair 2*fl, 2*fl+1
  int s = rp[r], d = deg[r];
  float a0 = 0.f, a1 = 0.f;
  int t = half;
  for (; t + 2 < d; t += 4) {
    uint2 e0 = edges[s + t];
    uint2 e1 = edges[s + t + 2];
    uint u0 = h2[(size_t)e0.x * 32 + fl];
    uint u1 = h2[(size_t)e1.x * 32 + fl];
    float v0 = __uint_as_float(e0.y), v1 = __uint_as_float(e1.y);
    a0 = fmaf(v0, bf_lo(u0), a0); a1 = fmaf(v0, bf_hi(u0), a1);
    a0 = fmaf(v1, bf_lo(u1), a0); a1 = fmaf(v1, bf_hi(u1), a1);
  }
  if (t < d) {
    uint2 e0 = edges[s + t];
    uint u0 = h2[(size_t)e0.x * 32 + fl];
    float v0 = __uint_as_float(e0.y);
    a0 = fmaf(v0, bf_lo(u0), a0); a1 = fmaf(v0, bf_hi(u0), a1);
  }
  a0 += __shfl_xor(a0, 32);
  a1 += __shfl_xor(a1, 32);
  if (half == 0) {
    float2 bb = ((const float2*)b2)[fl];
    ((float2*)out)[(size_t)r * 32 + fl] = make_float2(a0 + bb.x, a1 + bb.y);
  }
}

extern "C" void kernel_launch(void* const* d_in, const int* in_sizes, int n_in,
                              void* d_out, int out_size, void* d_ws, size_t ws_size,
                              hipStream_t stream) {
  const float* x        = (const float*)d_in[0];
  const float* w1       = (const float*)d_in[1];
  const float* b1       = (const float*)d_in[2];
  const float* w2       = (const float*)d_in[3];
  const float* b2       = (const float*)d_in[4];
  const int*   adj_row  = (const int*)d_in[5];
  const int*   adj_col  = (const int*)d_in[6];
  const float* adj_vals = (const float*)d_in[7];
  float* out = (float*)d_out;

  const int N  = in_sizes[0] / 256;   // 100000
  const int NE = in_sizes[5];         // 1600000

  char* p = (char*)d_ws;
  auto carve = [&](size_t bytes) {
    char* r = p;
    p += (bytes + 255) & ~(size_t)255;
    return (void*)r;
  };
  uint*  h      = (uint*) carve((size_t)N * 64 * 4);   // bf16 [N][128]
  uint*  agg    = (uint*) carve((size_t)N * 64 * 4);   // bf16 [N][128]
  uint2* edges  = (uint2*)carve((size_t)NE * 8);       // {col, val}
  int*   rp     = (int*)  carve((size_t)N * 4);
  int*   deg    = (int*)  carve((size_t)N * 4);
  int*   cursor = (int*)  carve((size_t)N * 4);
  int*   bsums  = (int*)  carve(1024);
  uint*  h2     = h;                                   // bf16 [N][64], h dead after spmm1

  const int nb_scan = (N + 1023) / 1024;

  hipLaunchKernelGGL(k_zero,       dim3((N + 255) / 256),  dim3(256), 0, stream, deg, N);
  hipLaunchKernelGGL(k_count,      dim3((NE + 255) / 256), dim3(256), 0, stream, adj_row, deg, NE);
  hipLaunchKernelGGL(k_scan_block, dim3(nb_scan),          dim3(256), 0, stream, deg, rp, bsums, N);
  hipLaunchKernelGGL(k_scan_sums,  dim3(1),                dim3(256), 0, stream, bsums, nb_scan);
  hipLaunchKernelGGL(k_scan_add,   dim3((N + 255) / 256),  dim3(256), 0, stream, rp, cursor, bsums, N);
  hipLaunchKernelGGL(k_scatter,    dim3((NE + 255) / 256), dim3(256), 0, stream,
                     adj_row, adj_col, adj_vals, cursor, edges, NE);

  hipLaunchKernelGGL(gemm1_kernel, dim3((N + 127) / 128),  dim3(256), 0, stream, x, w1, h, N);
  hipLaunchKernelGGL(k_spmm1,      dim3((N + 3) / 4),      dim3(256), 0, stream,
                     rp, deg, edges, h, b1, agg, N);
  hipLaunchKernelGGL(gemm2_kernel, dim3((N + 127) / 128),  dim3(256), 0, stream, agg, w2, h2, N);
  hipLaunchKernelGGL(k_spmm2,      dim3((N + 3) / 4),      dim3(256), 0, stream,
                     rp, deg, edges, h2, b2, out, N);
}

// Round 3
// 537.308 us; speedup vs baseline: 1.4171x; 1.1319x over previous
//
#include <hip/hip_runtime.h>

// GCN forward: h = relu(spmm(x@w1)+b1); out = spmm(h@w2)+b2
// CSR built on-device per launch. Intermediates bf16-packed.
// GEMMs: no-LDS direct-register bf16 MFMA (B pre-transposed to bf16, L2-resident).

typedef unsigned int uint;
typedef unsigned short ushort;
using bf16x8 = __attribute__((ext_vector_type(8))) short;
using f32x4  = __attribute__((ext_vector_type(4))) float;

union U8 { bf16x8 v; uint4 q; };

__device__ inline uint f2bf(float f) {
  uint u = __float_as_uint(f);
  return (u + 0x7fffu + ((u >> 16) & 1u)) >> 16;   // RNE
}
__device__ inline uint pkbf(float lo, float hi) { return f2bf(lo) | (f2bf(hi) << 16); }
__device__ inline float bf_lo(uint u) { return __uint_as_float(u << 16); }
__device__ inline float bf_hi(uint u) { return __uint_as_float(u & 0xffff0000u); }

// ---------------- weight transpose+cast (tiny) ----------------
__global__ void k_tr_w1(const float* __restrict__ w, ushort* __restrict__ wt) {
  int idx = blockIdx.x * 256 + threadIdx.x;      // 32768 = 256*128
  int k = idx >> 7, n = idx & 127;
  wt[n * 256 + k] = (ushort)f2bf(w[idx]);
}
__global__ void k_tr_w2(const float* __restrict__ w, ushort* __restrict__ wt) {
  int idx = blockIdx.x * 256 + threadIdx.x;      // 8192 = 128*64
  int k = idx >> 6, n = idx & 63;
  wt[n * 128 + k] = (ushort)f2bf(w[idx]);
}

// ---------------- CSR build ----------------
__global__ void k_zero(int* __restrict__ p, int n) {
  int i = blockIdx.x * blockDim.x + threadIdx.x;
  if (i < n) p[i] = 0;
}

__global__ void k_count(const int* __restrict__ row, int* __restrict__ deg, int ne) {
  int e = blockIdx.x * blockDim.x + threadIdx.x;
  if (e < ne) atomicAdd(&deg[row[e]], 1);
}

__global__ __launch_bounds__(256)
void k_scan_block(const int* __restrict__ deg, int* __restrict__ out,
                  int* __restrict__ bsums, int n) {
  __shared__ int sd[256];
  int t = threadIdx.x;
  int base = blockIdx.x * 1024 + t * 4;
  int v0 = (base + 0 < n) ? deg[base + 0] : 0;
  int v1 = (base + 1 < n) ? deg[base + 1] : 0;
  int v2 = (base + 2 < n) ? deg[base + 2] : 0;
  int v3 = (base + 3 < n) ? deg[base + 3] : 0;
  int s = v0 + v1 + v2 + v3;
  sd[t] = s;
  __syncthreads();
  for (int off = 1; off < 256; off <<= 1) {
    int x = (t >= off) ? sd[t - off] : 0;
    __syncthreads();
    sd[t] += x;
    __syncthreads();
  }
  int excl = sd[t] - s;
  if (base + 0 < n) out[base + 0] = excl;
  if (base + 1 < n) out[base + 1] = excl + v0;
  if (base + 2 < n) out[base + 2] = excl + v0 + v1;
  if (base + 3 < n) out[base + 3] = excl + v0 + v1 + v2;
  if (t == 255) bsums[blockIdx.x] = sd[255];
}

__global__ __launch_bounds__(256)
void k_scan_sums(int* __restrict__ bsums, int nb) {
  __shared__ int sd[256];
  int t = threadIdx.x;
  int v = (t < nb) ? bsums[t] : 0;
  sd[t] = v;
  __syncthreads();
  for (int off = 1; off < 256; off <<= 1) {
    int x = (t >= off) ? sd[t - off] : 0;
    __syncthreads();
    sd[t] += x;
    __syncthreads();
  }
  if (t < nb) bsums[t] = sd[t] - v;
}

__global__ void k_scan_add(int* __restrict__ rp, int* __restrict__ cursor,
                           const int* __restrict__ bsums, int n) {
  int i = blockIdx.x * blockDim.x + threadIdx.x;
  if (i < n) {
    int v = rp[i] + bsums[i >> 10];
    rp[i] = v;
    cursor[i] = v;
  }
}

__global__ void k_scatter(const int* __restrict__ row, const int* __restrict__ col,
                          const float* __restrict__ vals, int* __restrict__ cursor,
                          uint2* __restrict__ edges, int ne) {
  int e = blockIdx.x * blockDim.x + threadIdx.x;
  if (e < ne) {
    int r = row[e];
    int p = atomicAdd(&cursor[r], 1);
    uint2 ev;
    ev.x = (uint)col[e];
    ev.y = __float_as_uint(vals[e]);
    edges[p] = ev;
  }
}

// ---------------- GEMM1 (MFMA): h_bf16[M,128] = x[M,256] @ w1[256,128] ----------------
// No LDS. Per block: 128 rows, 4 waves x 32 rows. B from w1t bf16 [128][256] (L2).
__global__ __launch_bounds__(256)
void gemm1_mfma(const float* __restrict__ A, const ushort* __restrict__ Bt,
                uint* __restrict__ C, int M) {
  const int tid  = threadIdx.x;
  const int wid  = tid >> 6;
  const int lane = tid & 63;
  const int lr   = lane & 15;
  const int lk   = lane >> 4;
  const int m0   = blockIdx.x * 128 + wid * 32;

  f32x4 acc[2][8];
#pragma unroll
  for (int mf = 0; mf < 2; ++mf)
#pragma unroll
    for (int nf = 0; nf < 8; ++nf) acc[mf][nf] = (f32x4){0.f, 0.f, 0.f, 0.f};

  const int row0 = min(m0 + lr,      M - 1);
  const int row1 = min(m0 + 16 + lr, M - 1);
  const float*  a0p = A + (size_t)row0 * 256 + lk * 8;
  const float*  a1p = A + (size_t)row1 * 256 + lk * 8;
  const ushort* bp  = Bt + lr * 256 + lk * 8;

#pragma unroll
  for (int kk = 0; kk < 8; ++kk) {
    float4 x0 = *(const float4*)(a0p + kk * 32);
    float4 x1 = *(const float4*)(a0p + kk * 32 + 4);
    float4 y0 = *(const float4*)(a1p + kk * 32);
    float4 y1 = *(const float4*)(a1p + kk * 32 + 4);
    U8 a0, a1;
    a0.q = make_uint4(pkbf(x0.x, x0.y), pkbf(x0.z, x0.w), pkbf(x1.x, x1.y), pkbf(x1.z, x1.w));
    a1.q = make_uint4(pkbf(y0.x, y0.y), pkbf(y0.z, y0.w), pkbf(y1.x, y1.y), pkbf(y1.z, y1.w));
    bf16x8 b[8];
#pragma unroll
    for (int nf = 0; nf < 8; ++nf)
      b[nf] = *(const bf16x8*)(bp + nf * 4096 + kk * 32);
#pragma unroll
    for (int nf = 0; nf < 8; ++nf) {
      acc[0][nf] = __builtin_amdgcn_mfma_f32_16x16x32_bf16(a0.v, b[nf], acc[0][nf], 0, 0, 0);
      acc[1][nf] = __builtin_amdgcn_mfma_f32_16x16x32_bf16(a1.v, b[nf], acc[1][nf], 0, 0, 0);
    }
  }

  const bool evenl = (lr & 1) == 0;
#pragma unroll
  for (int mf = 0; mf < 2; ++mf)
#pragma unroll
    for (int nf = 0; nf < 8; ++nf)
#pragma unroll
      for (int j = 0; j < 4; ++j) {
        float own = acc[mf][nf][j];
        float oth = __shfl_xor(own, 1);
        int row = m0 + mf * 16 + lk * 4 + j;
        if (evenl && row < M)
          C[(size_t)row * 64 + nf * 8 + (lr >> 1)] = pkbf(own, oth);
      }
}

// ---------------- GEMM2 (MFMA): h2_bf16[M,64] = agg_bf16[M,128] @ w2[128,64] ----------------
__global__ __launch_bounds__(256)
void gemm2_mfma(const uint* __restrict__ A, const ushort* __restrict__ Bt,
                uint* __restrict__ C, int M) {
  const int tid  = threadIdx.x;
  const int wid  = tid >> 6;
  const int lane = tid & 63;
  const int lr   = lane & 15;
  const int lk   = lane >> 4;
  const int m0   = blockIdx.x * 128 + wid * 32;

  f32x4 acc[2][4];
#pragma unroll
  for (int mf = 0; mf < 2; ++mf)
#pragma unroll
    for (int nf = 0; nf < 4; ++nf) acc[mf][nf] = (f32x4){0.f, 0.f, 0.f, 0.f};

  const int row0 = min(m0 + lr,      M - 1);
  const int row1 = min(m0 + 16 + lr, M - 1);
  const ushort* A16 = (const ushort*)A;
  const ushort* a0p = A16 + (size_t)row0 * 128 + lk * 8;
  const ushort* a1p = A16 + (size_t)row1 * 128 + lk * 8;
  const ushort* bp  = Bt + lr * 128 + lk * 8;

#pragma unroll
  for (int kk = 0; kk < 4; ++kk) {
    bf16x8 a0 = *(const bf16x8*)(a0p + kk * 32);
    bf16x8 a1 = *(const bf16x8*)(a1p + kk * 32);
    bf16x8 b[4];
#pragma unroll
    for (int nf = 0; nf < 4; ++nf)
      b[nf] = *(const bf16x8*)(bp + nf * 2048 + kk * 32);
#pragma unroll
    for (int nf = 0; nf < 4; ++nf) {
      acc[0][nf] = __builtin_amdgcn_mfma_f32_16x16x32_bf16(a0, b[nf], acc[0][nf], 0, 0, 0);
      acc[1][nf] = __builtin_amdgcn_mfma_f32_16x16x32_bf16(a1, b[nf], acc[1][nf], 0, 0, 0);
    }
  }

  const bool evenl = (lr & 1) == 0;
#pragma unroll
  for (int mf = 0; mf < 2; ++mf)
#pragma unroll
    for (int nf = 0; nf < 4; ++nf)
#pragma unroll
      for (int j = 0; j < 4; ++j) {
        float own = acc[mf][nf][j];
        float oth = __shfl_xor(own, 1);
        int row = m0 + mf * 16 + lk * 4 + j;
        if (evenl && row < M)
          C[(size_t)row * 32 + nf * 8 + (lr >> 1)] = pkbf(own, oth);
      }
}

// ---------------- SPMM1 + relu(+b1): one wave/row, 128 feats bf16 ----------------
__global__ __launch_bounds__(256)
void k_spmm1(const int* __restrict__ rp, const int* __restrict__ deg,
             const uint2* __restrict__ edges, const uint* __restrict__ h,
             const float* __restrict__ b1, uint* __restrict__ agg, int n) {
  int r = blockIdx.x * 4 + (threadIdx.x >> 6);
  if (r >= n) return;
  int lane = threadIdx.x & 63;
  int s = rp[r], d = deg[r];
  float a0 = 0.f, a1 = 0.f;            // feats 2*lane, 2*lane+1
  int t = 0;
  for (; t + 4 <= d; t += 4) {
    uint2 e0 = edges[s + t + 0];
    uint2 e1 = edges[s + t + 1];
    uint2 e2 = edges[s + t + 2];
    uint2 e3 = edges[s + t + 3];
    uint u0 = h[(size_t)e0.x * 64 + lane];
    uint u1 = h[(size_t)e1.x * 64 + lane];
    uint u2 = h[(size_t)e2.x * 64 + lane];
    uint u3 = h[(size_t)e3.x * 64 + lane];
    float v0 = __uint_as_float(e0.y), v1 = __uint_as_float(e1.y);
    float v2 = __uint_as_float(e2.y), v3 = __uint_as_float(e3.y);
    a0 = fmaf(v0, bf_lo(u0), a0); a1 = fmaf(v0, bf_hi(u0), a1);
    a0 = fmaf(v1, bf_lo(u1), a0); a1 = fmaf(v1, bf_hi(u1), a1);
    a0 = fmaf(v2, bf_lo(u2), a0); a1 = fmaf(v2, bf_hi(u2), a1);
    a0 = fmaf(v3, bf_lo(u3), a0); a1 = fmaf(v3, bf_hi(u3), a1);
  }
  for (; t < d; ++t) {
    uint2 e0 = edges[s + t];
    uint u0 = h[(size_t)e0.x * 64 + lane];
    float v0 = __uint_as_float(e0.y);
    a0 = fmaf(v0, bf_lo(u0), a0); a1 = fmaf(v0, bf_hi(u0), a1);
  }
  float2 bb = ((const float2*)b1)[lane];
  float r0 = fmaxf(a0 + bb.x, 0.f);
  float r1 = fmaxf(a1 + bb.y, 0.f);
  agg[(size_t)r * 64 + lane] = pkbf(r0, r1);
}

// ---------------- SPMM2 + b2: one wave/row, 2 half-wave edge workers ----------------
__global__ __launch_bounds__(256)
void k_spmm2(const int* __restrict__ rp, const int* __restrict__ deg,
             const uint2* __restrict__ edges, const uint* __restrict__ h2,
             const float* __restrict__ b2, float* __restrict__ out, int n) {
  int r = blockIdx.x * 4 + (threadIdx.x >> 6);
  if (r >= n) return;
  int lane = threadIdx.x & 63;
  int half = lane >> 5;
  int fl = lane & 31;                  // feat pair 2*fl, 2*fl+1
  int s = rp[r], d = deg[r];
  float a0 = 0.f, a1 = 0.f;
  int t = half;
  for (; t + 2 < d; t += 4) {
    uint2 e0 = edges[s + t];
    uint2 e1 = edges[s + t + 2];
    uint u0 = h2[(size_t)e0.x * 32 + fl];
    uint u1 = h2[(size_t)e1.x * 32 + fl];
    float v0 = __uint_as_float(e0.y), v1 = __uint_as_float(e1.y);
    a0 = fmaf(v0, bf_lo(u0), a0); a1 = fmaf(v0, bf_hi(u0), a1);
    a0 = fmaf(v1, bf_lo(u1), a0); a1 = fmaf(v1, bf_hi(u1), a1);
  }
  if (t < d) {
    uint2 e0 = edges[s + t];
    uint u0 = h2[(size_t)e0.x * 32 + fl];
    float v0 = __uint_as_float(e0.y);
    a0 = fmaf(v0, bf_lo(u0), a0); a1 = fmaf(v0, bf_hi(u0), a1);
  }
  a0 += __shfl_xor(a0, 32);
  a1 += __shfl_xor(a1, 32);
  if (half == 0) {
    float2 bb = ((const float2*)b2)[fl];
    ((float2*)out)[(size_t)r * 32 + fl] = make_float2(a0 + bb.x, a1 + bb.y);
  }
}

extern "C" void kernel_launch(void* const* d_in, const int* in_sizes, int n_in,
                              void* d_out, int out_size, void* d_ws, size_t ws_size,
                              hipStream_t stream) {
  const float* x        = (const float*)d_in[0];
  const float* w1       = (const float*)d_in[1];
  const float* b1       = (const float*)d_in[2];
  const float* w2       = (const float*)d_in[3];
  const float* b2       = (const float*)d_in[4];
  const int*   adj_row  = (const int*)d_in[5];
  const int*   adj_col  = (const int*)d_in[6];
  const float* adj_vals = (const float*)d_in[7];
  float* out = (float*)d_out;

  const int N  = in_sizes[0] / 256;   // 100000
  const int NE = in_sizes[5];         // 1600000

  char* p = (char*)d_ws;
  auto carve = [&](size_t bytes) {
    char* r = p;
    p += (bytes + 255) & ~(size_t)255;
    return (void*)r;
  };
  uint*   h      = (uint*)  carve((size_t)N * 64 * 4);   // bf16 [N][128]
  uint*   agg    = (uint*)  carve((size_t)N * 64 * 4);   // bf16 [N][128]
  uint2*  edges  = (uint2*) carve((size_t)NE * 8);       // {col, val}
  int*    rp     = (int*)   carve((size_t)N * 4);
  int*    deg    = (int*)   carve((size_t)N * 4);
  int*    cursor = (int*)   carve((size_t)N * 4);
  int*    bsums  = (int*)   carve(1024);
  ushort* w1t    = (ushort*)carve(128 * 256 * 2);        // bf16 [128][256]
  ushort* w2t    = (ushort*)carve(64 * 128 * 2);         // bf16 [64][128]
  uint*   h2     = h;                                    // bf16 [N][64], h dead after spmm1

  const int nb_scan = (N + 1023) / 1024;

  hipLaunchKernelGGL(k_tr_w1,      dim3(128),              dim3(256), 0, stream, w1, w1t);
  hipLaunchKernelGGL(k_tr_w2,      dim3(32),               dim3(256), 0, stream, w2, w2t);
  hipLaunchKernelGGL(k_zero,       dim3((N + 255) / 256),  dim3(256), 0, stream, deg, N);
  hipLaunchKernelGGL(k_count,      dim3((NE + 255) / 256), dim3(256), 0, stream, adj_row, deg, NE);
  hipLaunchKernelGGL(k_scan_block, dim3(nb_scan),          dim3(256), 0, stream, deg, rp, bsums, N);
  hipLaunchKernelGGL(k_scan_sums,  dim3(1),                dim3(256), 0, stream, bsums, nb_scan);
  hipLaunchKernelGGL(k_scan_add,   dim3((N + 255) / 256),  dim3(256), 0, stream, rp, cursor, bsums, N);
  hipLaunchKernelGGL(k_scatter,    dim3((NE + 255) / 256), dim3(256), 0, stream,
                     adj_row, adj_col, adj_vals, cursor, edges, NE);

  hipLaunchKernelGGL(gemm1_mfma,   dim3((N + 127) / 128),  dim3(256), 0, stream, x, w1t, h, N);
  hipLaunchKernelGGL(k_spmm1,      dim3((N + 3) / 4),      dim3(256), 0, stream,
                     rp, deg, edges, h, b1, agg, N);
  hipLaunchKernelGGL(gemm2_mfma,   dim3((N + 127) / 128),  dim3(256), 0, stream, agg, w2t, h2, N);
  hipLaunchKernelGGL(k_spmm2,      dim3((N + 3) / 4),      dim3(256), 0, stream,
                     rp, deg, edges, h2, b2, out, N);
}